// Round 8
// baseline (5035.980 us; speedup 1.0000x reference)
//
#include <hip/hip_runtime.h>

#define TT   512
#define IDIM 64
#define HDIM 256
#define FAST_TRIES 96

typedef short  short8  __attribute__((ext_vector_type(8)));
typedef short  short4v __attribute__((ext_vector_type(4)));
typedef float  f32x4   __attribute__((ext_vector_type(4)));
typedef int    int4v   __attribute__((ext_vector_type(4)));
typedef unsigned int       u32;
typedef unsigned long long u64;

__device__ __forceinline__ short f2bf(float f) {
    unsigned u = __float_as_uint(f);
    u = u + 0x7FFFu + ((u >> 16) & 1u);   // round-to-nearest-even
    return (short)(u >> 16);
}
__device__ __forceinline__ u32 f2bf_u(float f) {
    unsigned u = __float_as_uint(f);
    u = u + 0x7FFFu + ((u >> 16) & 1u);
    return (u >> 16);
}
__device__ __forceinline__ float bf2f(short h) {
    return __uint_as_float(((unsigned)(unsigned short)h) << 16);
}
__device__ __forceinline__ float sigm(float x)  { return 1.0f / (1.0f + __expf(-x)); }
__device__ __forceinline__ float tanh_(float x) { return 2.0f / (1.0f + __expf(-2.0f * x)) - 1.0f; }

// 256 persistent wgs = 16 cliques (batch-groups, blk%8-partitioned: SPX
// round-robin should co-locate each clique on one XCD) x 16 hidden-chunks.
// Tagged-word exchange: u64 = (h1_bf16<<16|tag):(h0_bf16<<16|tag); parity
// double-buffer; skew<=1 step. Dual publish: hfast (plain store -> writer's
// XCD write-back L2) + hslow (agent/sc1 -> MALL, proven live). Readers poll
// hfast with sc0 loads (bypass L1, read shared XCD L2).
//   s==0: clock64-bounded generous budget (doubles as the arrival latch).
//   s>=1: 96 sweeps; "success" slower than DEMOTE_CYC (eviction-paced,
//         i.e. cross-XCD) takes a strike; 2 strikes or a timeout -> permanent
//         per-thread demotion to the unbounded sc1 poll (proven live).
// Fast threads defer their sc1 publish until after gather (off the poll's
// vmcnt(0) path); slow/demoting threads publish sc1 immediately (liveness).
__global__ __launch_bounds__(256, 1) void lstm_fused(
    const float* __restrict__ x,
    const float* __restrict__ Wih0, const float* __restrict__ Whh0,
    const float* __restrict__ bih0, const float* __restrict__ bhh0,
    const float* __restrict__ Wih1, const float* __restrict__ Whh1,
    const float* __restrict__ bih1, const float* __restrict__ bhh1,
    const float* __restrict__ Wfc,  const float* __restrict__ bfc,
    float* __restrict__ out, char* __restrict__ ws)
{
    u64* hfast = (u64*)ws;                        // [2][16][16][256] u64 (1 MB)
    u64* hslow = (u64*)(ws + 1024 * 1024);        // [2][16][16][256] u64 (1 MB)

    const int blk   = blockIdx.x;                 // 0..255
    const int grp   = (blk & 7) + 8 * (blk >> 7); // clique 0..15; same blk%8 => same XCD (SPX round-robin hypothesis)
    const int chunk = (blk >> 3) & 15;            // hidden-chunk 0..15
    const int tid   = threadIdx.x;
    const int lane  = tid & 63;
    const int wave  = tid >> 6;      // gate index: 0=i 1=f 2=g 3=o
    const int quad  = lane >> 4;
    const int nn    = lane & 15;

    __shared__ short A0[16][328];       // [m][ x(64) | h0(256) ] + pad
    __shared__ short A1[16][520];       // [m][ h0(256) | h1(256) ] + pad
    __shared__ float gbuf[2][4][16][17];
    __shared__ float red[16][16];
    __shared__ float ldspad[12288];     // force 1 wg/CU (total LDS > 80 KiB)

    for (int i = tid; i < 16 * 328; i += 256) (&A0[0][0])[i] = 0;
    for (int i = tid; i < 16 * 520; i += 256) (&A1[0][0])[i] = 0;

    // ---- static weight fragments -> registers (B operand: W[n][k]) ----
    const int wrow = wave * HDIM + chunk * 16 + nn;
    short8 w0f[10];   // layer0: kb 0..1 = Wih0 (K 0..63), kb 2..9 = Whh0
    short8 w1f[16];   // layer1: kb 0..7 = Wih1, kb 8..15 = Whh1
#pragma unroll
    for (int kb = 0; kb < 10; ++kb)
#pragma unroll
        for (int j = 0; j < 8; ++j) {
            int k = kb * 32 + quad * 8 + j;
            float v = (k < 64) ? Wih0[wrow * IDIM + k] : Whh0[wrow * HDIM + (k - 64)];
            w0f[kb][j] = f2bf(v);
        }
#pragma unroll
    for (int kb = 0; kb < 16; ++kb)
#pragma unroll
        for (int j = 0; j < 8; ++j) {
            int k = kb * 32 + quad * 8 + j;
            float v = (k < 256) ? Wih1[wrow * HDIM + k] : Whh1[wrow * HDIM + (k - 256)];
            w1f[kb][j] = f2bf(v);
        }
    const float bias0 = bih0[wrow] + bhh0[wrow];
    const float bias1 = bih1[wrow] + bhh1[wrow];

    const int em = tid >> 4;   // batch row 0..15
    const int ej = tid & 15;   // hidden unit group 0..15
    float c0 = 0.0f, c1 = 0.0f;
    bool useFast = true;
    int  strikes = 0;

    // x(0) straight to LDS; xv register holds x(s+1) entering step s
    {
        const float4 v = *(const float4*)&x[((size_t)(grp * 16 + em) * TT) * IDIM + ej * 4];
        short4v sv;
        sv[0] = f2bf(v.x); sv[1] = f2bf(v.y); sv[2] = f2bf(v.z); sv[3] = f2bf(v.w);
        *(short4v*)&A0[em][ej * 4] = sv;
    }
    float4 xv = *(const float4*)&x[((size_t)(grp * 16 + em) * TT + 1) * IDIM + ej * 4];
    __syncthreads();

    // super-step s: layer0 -> h0[s] (s<T); layer1 -> h1[s-1] (s>=1)
    for (int s = 0; s <= TT; ++s) {
        const int par = s & 1;
        const u32 tag = (u32)(s + 1);   // 1..513; poison low16=0xAAAA never matches

        if (s < TT) {
            f32x4 acc = {0.f, 0.f, 0.f, 0.f};
#pragma unroll
            for (int kb = 0; kb < 10; ++kb) {
                short8 a = *(const short8*)&A0[nn][kb * 32 + quad * 8];
                acc = __builtin_amdgcn_mfma_f32_16x16x32_bf16(a, w0f[kb], acc, 0, 0, 0);
            }
#pragma unroll
            for (int r = 0; r < 4; ++r)
                gbuf[0][wave][quad * 4 + r][nn] = acc[r] + bias0;
        }
        if (s >= 1) {
            f32x4 acc = {0.f, 0.f, 0.f, 0.f};
#pragma unroll
            for (int kb = 0; kb < 16; ++kb) {
                short8 a = *(const short8*)&A1[nn][kb * 32 + quad * 8];
                acc = __builtin_amdgcn_mfma_f32_16x16x32_bf16(a, w1f[kb], acc, 0, 0, 0);
            }
#pragma unroll
            for (int r = 0; r < 4; ++r)
                gbuf[1][wave][quad * 4 + r][nn] = acc[r] + bias1;
        }
        __syncthreads();

        // ---- elementwise cell updates -> one tagged u64 per unit ----
        u32 h0word = tag, h1word = tag;   // dummy payload 0 at s==TT / s==0
        if (s < TT) {
            float gi = sigm (gbuf[0][0][em][ej]);
            float gf = sigm (gbuf[0][1][em][ej]);
            float gg = tanh_(gbuf[0][2][em][ej]);
            float go = sigm (gbuf[0][3][em][ej]);
            c0 = gf * c0 + gi * gg;
            h0word = (f2bf_u(go * tanh_(c0)) << 16) | tag;
        }
        if (s >= 1) {
            float gi = sigm (gbuf[1][0][em][ej]);
            float gf = sigm (gbuf[1][1][em][ej]);
            float gg = tanh_(gbuf[1][2][em][ej]);
            float go = sigm (gbuf[1][3][em][ej]);
            c1 = gf * c1 + gi * gg;
            h1word = (f2bf_u(go * tanh_(c1)) << 16) | tag;
        }
        const u64 pub = ((u64)h1word << 32) | (u64)h0word;
        const size_t widx = ((size_t)(par * 16 + grp) * 16 + em) * 256 + chunk * 16 + ej;
        __hip_atomic_store(&hfast[widx], pub, __ATOMIC_RELAXED, __HIP_MEMORY_SCOPE_WORKGROUP);
        if (!useFast)   // slow threads publish sc1 immediately (liveness)
            __hip_atomic_store(&hslow[widx], pub, __ATOMIC_RELAXED, __HIP_MEMORY_SCOPE_AGENT);

        // x(s+1) -> LDS (A0 x-region already consumed by this step's MFMA)
        if (s + 1 < TT) {
            short4v sv;
            sv[0] = f2bf(xv.x); sv[1] = f2bf(xv.y); sv[2] = f2bf(xv.z); sv[3] = f2bf(xv.w);
            *(short4v*)&A0[em][ej * 4] = sv;
        }

        // ---- gather tag s+1: 16 u64 (peer chunk ej, row em) ----
        const size_t ridx = ((size_t)(par * 16 + grp) * 16 + em) * 256 + ej * 16;
        int4v q[8];
        bool got = false;
        if (useFast) {
            const u64* rp = &hfast[ridx];
            const long long t0 = clock64();
            int trial = 0;
            for (;;) {
                asm volatile(
                    "global_load_dwordx4 %0, %8, off sc0\n\t"
                    "global_load_dwordx4 %1, %8, off offset:16 sc0\n\t"
                    "global_load_dwordx4 %2, %8, off offset:32 sc0\n\t"
                    "global_load_dwordx4 %3, %8, off offset:48 sc0\n\t"
                    "global_load_dwordx4 %4, %8, off offset:64 sc0\n\t"
                    "global_load_dwordx4 %5, %8, off offset:80 sc0\n\t"
                    "global_load_dwordx4 %6, %8, off offset:96 sc0\n\t"
                    "global_load_dwordx4 %7, %8, off offset:112 sc0\n\t"
                    "s_waitcnt vmcnt(0)"
                    : "=&v"(q[0]), "=&v"(q[1]), "=&v"(q[2]), "=&v"(q[3]),
                      "=&v"(q[4]), "=&v"(q[5]), "=&v"(q[6]), "=&v"(q[7])
                    : "v"(rp)
                    : "memory");
                u32 bad = 0;
#pragma unroll
                for (int i = 0; i < 8; ++i)
                    bad |= (((u32)q[i][0] ^ tag) & 0xFFFFu) | (((u32)q[i][1] ^ tag) & 0xFFFFu)
                         | (((u32)q[i][2] ^ tag) & 0xFFFFu) | (((u32)q[i][3] ^ tag) & 0xFFFFu);
                if (!bad) { got = true; break; }
                ++trial;
                if (s == 0) {
                    if (clock64() - t0 > 1500000LL) break;   // bounded arrival latch
                } else {
                    if (trial >= FAST_TRIES) break;
                }
            }
            if (got) {
                if (s >= 1 && (clock64() - t0) > 6000LL) {
                    if (++strikes >= 2) useFast = false;   // eviction-paced: not my XCD
                } else {
                    strikes = 0;
                }
                // deferred sc1 publish (off the poll path; peers' liveness)
                __hip_atomic_store(&hslow[widx], pub, __ATOMIC_RELAXED, __HIP_MEMORY_SCOPE_AGENT);
            } else {
                __hip_atomic_store(&hslow[widx], pub, __ATOMIC_RELAXED, __HIP_MEMORY_SCOPE_AGENT);
                useFast = false;
            }
        }
        if (!got) {
            const u64* rp = &hslow[ridx];
            for (;;) {
                u64 r[16];
#pragma unroll
                for (int i = 0; i < 16; ++i)
                    r[i] = __hip_atomic_load(&rp[i], __ATOMIC_RELAXED, __HIP_MEMORY_SCOPE_AGENT);
                u32 bad = 0;
#pragma unroll
                for (int i = 0; i < 16; ++i)
                    bad |= (((u32)r[i] ^ tag) & 0xFFFFu)
                         | ((((u32)(r[i] >> 32)) ^ tag) & 0xFFFFu);
                if (!bad) {
#pragma unroll
                    for (int i = 0; i < 8; ++i) {
                        q[i][0] = (int)(u32)r[2 * i];
                        q[i][1] = (int)(u32)(r[2 * i] >> 32);
                        q[i][2] = (int)(u32)r[2 * i + 1];
                        q[i][3] = (int)(u32)(r[2 * i + 1] >> 32);
                    }
                    break;
                }
            }
        }

        // prefetch x(s+2): overlaps unpack/compute; retired before next poll
        if (s + 2 < TT)
            xv = *(const float4*)&x[((size_t)(grp * 16 + em) * TT + (s + 2)) * IDIM + ej * 4];

        // ---- unpack: h0 -> A0[64+..]/A1[0..255], h1 -> A1[256..511] ----
        {
            u32 w0[8], w1[8];
#pragma unroll
            for (int i = 0; i < 8; ++i) {
                w0[i] = (((u32)q[i][0]) >> 16) | (((u32)q[i][2]) & 0xFFFF0000u);
                w1[i] = (((u32)q[i][1]) >> 16) | (((u32)q[i][3]) & 0xFFFF0000u);
            }
            uint4 q0 = {w0[0], w0[1], w0[2], w0[3]};
            uint4 q1 = {w0[4], w0[5], w0[6], w0[7]};
            *(uint4*)&A0[em][64 + ej * 16]     = q0;
            *(uint4*)&A0[em][64 + ej * 16 + 8] = q1;
            *(uint4*)&A1[em][ej * 16]          = q0;
            *(uint4*)&A1[em][ej * 16 + 8]      = q1;
            uint4 q2 = {w1[0], w1[1], w1[2], w1[3]};
            uint4 q3 = {w1[4], w1[5], w1[6], w1[7]};
            *(uint4*)&A1[em][256 + ej * 16]     = q2;
            *(uint4*)&A1[em][256 + ej * 16 + 8] = q3;
        }
        __syncthreads();
    }

    // ---- FC epilogue: A1[:,256..511] holds h1[T-1] (bf16) ----
    {
        float part = 0.f;
#pragma unroll
        for (int kk = 0; kk < 16; ++kk) {
            int k = ej * 16 + kk;
            part += bf2f(A1[em][256 + k]) * Wfc[k];
        }
        red[em][ej] = part;
    }
    __syncthreads();
    if (chunk == 0 && tid < 16) {
        float sum = bfc[0];
#pragma unroll
        for (int c = 0; c < 16; ++c) sum += red[tid][c];
        out[grp * 16 + tid] = sum;
    }

    // keep ldspad allocated (1 wg/CU); never true at runtime
    if (gridDim.x > 100000) { ldspad[tid] = bias0; out[0] = ldspad[255 - tid]; }
}

extern "C" void kernel_launch(void* const* d_in, const int* in_sizes, int n_in,
                              void* d_out, int out_size, void* d_ws, size_t ws_size,
                              hipStream_t stream) {
    (void)in_sizes; (void)n_in; (void)out_size; (void)ws_size;
    const float* x    = (const float*)d_in[0];
    const float* Wih0 = (const float*)d_in[1];
    const float* Whh0 = (const float*)d_in[2];
    const float* bih0 = (const float*)d_in[3];
    const float* bhh0 = (const float*)d_in[4];
    const float* Wih1 = (const float*)d_in[5];
    const float* Whh1 = (const float*)d_in[6];
    const float* bih1 = (const float*)d_in[7];
    const float* bhh1 = (const float*)d_in[8];
    const float* Wfc  = (const float*)d_in[9];
    const float* bfc  = (const float*)d_in[10];

    lstm_fused<<<256, 256, 0, stream>>>(x, Wih0, Whh0, bih0, bhh0,
                                        Wih1, Whh1, bih1, bhh1, Wfc, bfc,
                                        (float*)d_out, (char*)d_ws);
}

// Round 9
// 3517.437 us; speedup vs baseline: 1.4317x; 1.4317x over previous
//
#include <hip/hip_runtime.h>

#define TT   512
#define IDIM 64
#define HDIM 256

typedef short  short8  __attribute__((ext_vector_type(8)));
typedef short  short4v __attribute__((ext_vector_type(4)));
typedef float  f32x4   __attribute__((ext_vector_type(4)));
typedef int    int4v   __attribute__((ext_vector_type(4)));
typedef unsigned int       u32;
typedef unsigned long long u64;

__device__ __forceinline__ short f2bf(float f) {
    unsigned u = __float_as_uint(f);
    u = u + 0x7FFFu + ((u >> 16) & 1u);   // round-to-nearest-even
    return (short)(u >> 16);
}
__device__ __forceinline__ u32 f2bf_u(float f) {
    unsigned u = __float_as_uint(f);
    u = u + 0x7FFFu + ((u >> 16) & 1u);
    return (u >> 16);
}
__device__ __forceinline__ float bf2f(short h) {
    return __uint_as_float(((unsigned)(unsigned short)h) << 16);
}
__device__ __forceinline__ float sigm(float x)  { return 1.0f / (1.0f + __expf(-x)); }
__device__ __forceinline__ float tanh_(float x) { return 2.0f / (1.0f + __expf(-2.0f * x)) - 1.0f; }

// 256 persistent wgs = 16 cliques of 16 CONSECUTIVE blocks (contiguous-dispatch
// hypothesis: blocks 32g..32g+31 -> XCD g, so a 16-block clique is same-XCD).
// Tagged-word exchange: u64 = (h1<<16|tag15):(h0<<16|tag15); tag compare masks
// bit15 (vote bit). Parity double-buffer; skew<=1 step.
// Steps 0..8 = WINDOW: publish hfast(plain)+hslow(sc1); gather via hslow
// (proven live). Steps 0..7: probe hfast with one sc0 sweep AFTER slow gather
// (same-XCD => hfast, stored first, must already be visible; cross-XCD shows
// only at ~7us L2-eviction pace => probe fails). Step 8: wg-wide probe verdict
// stamped in tag bit15; all wgs extract all 16 votes from the same gather ->
// UNANIMOUS mode decision. FAST: hfast-only publish + unbounded sc0 poll
// (live: everyone always publishes hfast; worst case eviction-paced).
// SLOW: exactly the R3 sc1 path. No mixed mode, no per-thread demotion.
__global__ __launch_bounds__(256, 1) void lstm_fused(
    const float* __restrict__ x,
    const float* __restrict__ Wih0, const float* __restrict__ Whh0,
    const float* __restrict__ bih0, const float* __restrict__ bhh0,
    const float* __restrict__ Wih1, const float* __restrict__ Whh1,
    const float* __restrict__ bih1, const float* __restrict__ bhh1,
    const float* __restrict__ Wfc,  const float* __restrict__ bfc,
    float* __restrict__ out, char* __restrict__ ws)
{
    u64* hfast = (u64*)ws;                        // [2][16][16][256] u64 (1 MB)
    u64* hslow = (u64*)(ws + (1u << 20));         // [2][16][16][256] u64 (1 MB)

    const int blk   = blockIdx.x;   // 0..255
    const int grp   = blk >> 4;     // clique 0..15 = 16 CONSECUTIVE blocks
    const int chunk = blk & 15;     // hidden-chunk 0..15
    const int tid   = threadIdx.x;
    const int lane  = tid & 63;
    const int wave  = tid >> 6;     // gate index: 0=i 1=f 2=g 3=o
    const int quad  = lane >> 4;
    const int nn    = lane & 15;

    __shared__ short A0[16][328];       // [m][ x(64) | h0(256) ] + pad
    __shared__ short A1[16][520];       // [m][ h0(256) | h1(256) ] + pad
    __shared__ float gbuf[2][4][16][17];
    __shared__ float red[16][16];
    __shared__ int   s_vote[2];         // [0]=own-wg probe AND, [1]=clique AND
    __shared__ float ldspad[12288];     // force 1 wg/CU (total LDS > 80 KiB)

    for (int i = tid; i < 16 * 328; i += 256) (&A0[0][0])[i] = 0;
    for (int i = tid; i < 16 * 520; i += 256) (&A1[0][0])[i] = 0;
    if (tid == 0) { s_vote[0] = 1; s_vote[1] = 1; }

    // ---- static weight fragments -> registers (B operand: W[n][k]) ----
    const int wrow = wave * HDIM + chunk * 16 + nn;
    short8 w0f[10];   // layer0: kb 0..1 = Wih0 (K 0..63), kb 2..9 = Whh0
    short8 w1f[16];   // layer1: kb 0..7 = Wih1, kb 8..15 = Whh1
#pragma unroll
    for (int kb = 0; kb < 10; ++kb)
#pragma unroll
        for (int j = 0; j < 8; ++j) {
            int k = kb * 32 + quad * 8 + j;
            float v = (k < 64) ? Wih0[wrow * IDIM + k] : Whh0[wrow * HDIM + (k - 64)];
            w0f[kb][j] = f2bf(v);
        }
#pragma unroll
    for (int kb = 0; kb < 16; ++kb)
#pragma unroll
        for (int j = 0; j < 8; ++j) {
            int k = kb * 32 + quad * 8 + j;
            float v = (k < 256) ? Wih1[wrow * HDIM + k] : Whh1[wrow * HDIM + (k - 256)];
            w1f[kb][j] = f2bf(v);
        }
    const float bias0 = bih0[wrow] + bhh0[wrow];
    const float bias1 = bih1[wrow] + bhh1[wrow];

    const int em = tid >> 4;   // batch row 0..15
    const int ej = tid & 15;   // hidden unit group / peer-chunk id 0..15
    float c0 = 0.0f, c1 = 0.0f;
    bool probeOK  = true;
    bool fastMode = false;

    // x(0) -> LDS; xv holds x(s+1) entering step s
    {
        const float4 v = *(const float4*)&x[((size_t)(grp * 16 + em) * TT) * IDIM + ej * 4];
        short4v sv;
        sv[0] = f2bf(v.x); sv[1] = f2bf(v.y); sv[2] = f2bf(v.z); sv[3] = f2bf(v.w);
        *(short4v*)&A0[em][ej * 4] = sv;
    }
    float4 xv = *(const float4*)&x[((size_t)(grp * 16 + em) * TT + 1) * IDIM + ej * 4];
    __syncthreads();

    // one sc0 sweep of hfast[ridx..+15]; fills qq; returns all-tags-match
    auto sweep_fast = [&](const u64* rp, u32 tag, int4v* qq) -> bool {
        asm volatile(
            "global_load_dwordx4 %0, %8, off sc0\n\t"
            "global_load_dwordx4 %1, %8, off offset:16 sc0\n\t"
            "global_load_dwordx4 %2, %8, off offset:32 sc0\n\t"
            "global_load_dwordx4 %3, %8, off offset:48 sc0\n\t"
            "global_load_dwordx4 %4, %8, off offset:64 sc0\n\t"
            "global_load_dwordx4 %5, %8, off offset:80 sc0\n\t"
            "global_load_dwordx4 %6, %8, off offset:96 sc0\n\t"
            "global_load_dwordx4 %7, %8, off offset:112 sc0\n\t"
            "s_waitcnt vmcnt(0)"
            : "=&v"(qq[0]), "=&v"(qq[1]), "=&v"(qq[2]), "=&v"(qq[3]),
              "=&v"(qq[4]), "=&v"(qq[5]), "=&v"(qq[6]), "=&v"(qq[7])
            : "v"(rp)
            : "memory");
        u32 bad = 0;
#pragma unroll
        for (int i = 0; i < 8; ++i)
            bad |= (((u32)qq[i][0] ^ tag) & 0x7FFFu) | (((u32)qq[i][1] ^ tag) & 0x7FFFu)
                 | (((u32)qq[i][2] ^ tag) & 0x7FFFu) | (((u32)qq[i][3] ^ tag) & 0x7FFFu);
        return bad == 0;
    };

    // super-step s: layer0 -> h0[s] (s<T); layer1 -> h1[s-1] (s>=1)
    for (int s = 0; s <= TT; ++s) {
        const int par = s & 1;
        const u32 tag = (u32)(s + 1);   // 1..513 < 2^15; poison&0x7FFF=0x2AAA never matches

        if (s == 8 && !probeOK) s_vote[0] = 0;      // own-wg vote (pre-barrier write)
        if (s == 9) fastMode = (s_vote[1] != 0);    // unanimous clique decision

        if (s < TT) {
            f32x4 acc = {0.f, 0.f, 0.f, 0.f};
#pragma unroll
            for (int kb = 0; kb < 10; ++kb) {
                short8 a = *(const short8*)&A0[nn][kb * 32 + quad * 8];
                acc = __builtin_amdgcn_mfma_f32_16x16x32_bf16(a, w0f[kb], acc, 0, 0, 0);
            }
#pragma unroll
            for (int r = 0; r < 4; ++r)
                gbuf[0][wave][quad * 4 + r][nn] = acc[r] + bias0;
        }
        if (s >= 1) {
            f32x4 acc = {0.f, 0.f, 0.f, 0.f};
#pragma unroll
            for (int kb = 0; kb < 16; ++kb) {
                short8 a = *(const short8*)&A1[nn][kb * 32 + quad * 8];
                acc = __builtin_amdgcn_mfma_f32_16x16x32_bf16(a, w1f[kb], acc, 0, 0, 0);
            }
#pragma unroll
            for (int r = 0; r < 4; ++r)
                gbuf[1][wave][quad * 4 + r][nn] = acc[r] + bias1;
        }
        __syncthreads();   // gbuf ready; also orders s_vote[0] write < publish read

        // ---- elementwise cell updates -> one tagged u64 per unit ----
        u32 h0word = tag, h1word = tag;   // dummy payload 0 at s==TT / s==0
        if (s < TT) {
            float gi = sigm (gbuf[0][0][em][ej]);
            float gf = sigm (gbuf[0][1][em][ej]);
            float gg = tanh_(gbuf[0][2][em][ej]);
            float go = sigm (gbuf[0][3][em][ej]);
            c0 = gf * c0 + gi * gg;
            h0word = (f2bf_u(go * tanh_(c0)) << 16) | tag;
        }
        if (s >= 1) {
            float gi = sigm (gbuf[1][0][em][ej]);
            float gf = sigm (gbuf[1][1][em][ej]);
            float gg = tanh_(gbuf[1][2][em][ej]);
            float go = sigm (gbuf[1][3][em][ej]);
            c1 = gf * c1 + gi * gg;
            h1word = (f2bf_u(go * tanh_(c1)) << 16) | tag;
        }
        if (s == 8) {                      // stamp own-wg vote into bit15 of both tags
            u32 v = (u32)(s_vote[0] & 1) << 15;
            h0word |= v; h1word |= v;
        }
        const u64 pub = ((u64)h1word << 32) | (u64)h0word;
        const size_t widx = ((size_t)(par * 16 + grp) * 16 + em) * 256 + chunk * 16 + ej;
        __hip_atomic_store(&hfast[widx], pub, __ATOMIC_RELAXED, __HIP_MEMORY_SCOPE_WORKGROUP);
        if (s <= 8 || !fastMode)
            __hip_atomic_store(&hslow[widx], pub, __ATOMIC_RELAXED, __HIP_MEMORY_SCOPE_AGENT);

        // x(s+1) -> LDS (A0 x-region already consumed by this step's MFMA)
        if (s + 1 < TT) {
            short4v sv;
            sv[0] = f2bf(xv.x); sv[1] = f2bf(xv.y); sv[2] = f2bf(xv.z); sv[3] = f2bf(xv.w);
            *(short4v*)&A0[em][ej * 4] = sv;
        }

        // ---- gather tag s+1: 16 u64 (peer chunk ej, row em) ----
        const size_t ridx = ((size_t)(par * 16 + grp) * 16 + em) * 256 + ej * 16;
        int4v q[8];   // q[i] = {h0w(2i), h1w(2i), h0w(2i+1), h1w(2i+1)}
        if (s <= 8 || !fastMode) {
            const u64* rp = &hslow[ridx];
            for (;;) {
                u64 r[16];
#pragma unroll
                for (int i = 0; i < 16; ++i)
                    r[i] = __hip_atomic_load(&rp[i], __ATOMIC_RELAXED, __HIP_MEMORY_SCOPE_AGENT);
                u32 bad = 0;
#pragma unroll
                for (int i = 0; i < 16; ++i)
                    bad |= (((u32)r[i] ^ tag) & 0x7FFFu)
                         | ((((u32)(r[i] >> 32)) ^ tag) & 0x7FFFu);
                if (!bad) {
#pragma unroll
                    for (int i = 0; i < 8; ++i) {
                        q[i][0] = (int)(u32)r[2 * i];
                        q[i][1] = (int)(u32)(r[2 * i] >> 32);
                        q[i][2] = (int)(u32)r[2 * i + 1];
                        q[i][3] = (int)(u32)(r[2 * i + 1] >> 32);
                    }
                    if (s == 8) {   // extract peer ej's vote (bit15 of every half)
                        u32 vb = 0xFFFFFFFFu;
#pragma unroll
                        for (int i = 0; i < 16; ++i)
                            vb &= (u32)(r[i] >> 15) & (u32)(r[i] >> 47);
                        if (!(vb & 1u)) s_vote[1] = 0;   // benign same-value race
                    }
                    break;
                }
            }
            if (s < 8) {   // probe: same-XCD => hfast (stored first) already visible
                int4v p[8];
                probeOK = probeOK && sweep_fast(&hfast[ridx], tag, p);
            }
        } else {
            const u64* rp = &hfast[ridx];
            while (!sweep_fast(rp, tag, q)) {}
        }

        // prefetch x(s+2): overlaps unpack; retired before next step's poll
        if (s + 2 < TT)
            xv = *(const float4*)&x[((size_t)(grp * 16 + em) * TT + (s + 2)) * IDIM + ej * 4];

        // ---- unpack (payload = high16; vote/tag bits live in low16 only) ----
        {
            u32 w0[8], w1[8];
#pragma unroll
            for (int i = 0; i < 8; ++i) {
                w0[i] = (((u32)q[i][0]) >> 16) | (((u32)q[i][2]) & 0xFFFF0000u);
                w1[i] = (((u32)q[i][1]) >> 16) | (((u32)q[i][3]) & 0xFFFF0000u);
            }
            uint4 q0 = {w0[0], w0[1], w0[2], w0[3]};
            uint4 q1 = {w0[4], w0[5], w0[6], w0[7]};
            *(uint4*)&A0[em][64 + ej * 16]     = q0;
            *(uint4*)&A0[em][64 + ej * 16 + 8] = q1;
            *(uint4*)&A1[em][ej * 16]          = q0;
            *(uint4*)&A1[em][ej * 16 + 8]      = q1;
            uint4 q2 = {w1[0], w1[1], w1[2], w1[3]};
            uint4 q3 = {w1[4], w1[5], w1[6], w1[7]};
            *(uint4*)&A1[em][256 + ej * 16]     = q2;
            *(uint4*)&A1[em][256 + ej * 16 + 8] = q3;
        }
        __syncthreads();   // also orders step-8 s_vote[1] writes < step-9 read
    }

    // ---- FC epilogue: A1[:,256..511] holds h1[T-1] (bf16) ----
    {
        float part = 0.f;
#pragma unroll
        for (int kk = 0; kk < 16; ++kk) {
            int k = ej * 16 + kk;
            part += bf2f(A1[em][256 + k]) * Wfc[k];
        }
        red[em][ej] = part;
    }
    __syncthreads();
    if (chunk == 0 && tid < 16) {
        float sum = bfc[0];
#pragma unroll
        for (int c = 0; c < 16; ++c) sum += red[tid][c];
        out[grp * 16 + tid] = sum;
    }

    // keep ldspad allocated (1 wg/CU); never true at runtime
    if (gridDim.x > 100000) { ldspad[tid] = bias0; out[0] = ldspad[255 - tid]; }
}

extern "C" void kernel_launch(void* const* d_in, const int* in_sizes, int n_in,
                              void* d_out, int out_size, void* d_ws, size_t ws_size,
                              hipStream_t stream) {
    (void)in_sizes; (void)n_in; (void)out_size; (void)ws_size;
    const float* x    = (const float*)d_in[0];
    const float* Wih0 = (const float*)d_in[1];
    const float* Whh0 = (const float*)d_in[2];
    const float* bih0 = (const float*)d_in[3];
    const float* bhh0 = (const float*)d_in[4];
    const float* Wih1 = (const float*)d_in[5];
    const float* Whh1 = (const float*)d_in[6];
    const float* bih1 = (const float*)d_in[7];
    const float* bhh1 = (const float*)d_in[8];
    const float* Wfc  = (const float*)d_in[9];
    const float* bfc  = (const float*)d_in[10];

    lstm_fused<<<256, 256, 0, stream>>>(x, Wih0, Whh0, bih0, bhh0,
                                        Wih1, Whh1, bih1, bhh1, Wfc, bfc,
                                        (float*)d_out, (char*)d_ws);
}